// Round 1
// baseline (128.397 us; speedup 1.0000x reference)
//
#include <hip/hip_runtime.h>

#define N_ROWS 16384
#define NCB    16
#define CB     1024

// Zeros the 4 scalar tail outputs (rate_uem accumulator + 3 literal zeros).
__global__ void zero_tail_kernel(float* p) {
    int t = threadIdx.x;
    if (t < 4) p[t] = 0.0f;
}

__global__ __launch_bounds__(256) void ecvq_kernel(
    const float4* __restrict__ x,       // (N*NCB) float4 rows of dim 4
    const float4* __restrict__ cbook,   // (NCB*CB) float4 codewords
    const float*  __restrict__ logits,  // (NCB*CB)
    const float*  __restrict__ lmbda_p, // 1 element
    float4* __restrict__ xhat,          // (N*NCB) float4
    float*  __restrict__ tail)          // [rate_uem, rate_cem, prior_dist, param_bit]
{
    __shared__ float4 s_cb[CB];    // codewords for this cb-group      (16 KB)
    __shared__ float  s_cnb[CB];   // ||c||^2 + log2pmf/lmbda          ( 4 KB)
    __shared__ float  s_l2u[CB];   // -log2 pmf                        ( 4 KB)
    __shared__ float  sredA[4];
    __shared__ float  sredB[4];

    const int a     = blockIdx.x;   // codebook group 0..15
    const int chunk = blockIdx.y;   // row chunk 0..15 (1024 rows each)
    const int t     = threadIdx.x;  // 0..255

    // ---- stage codebook + compute log-softmax constants (redundant per chunk; cheap) ----
    float  l[4];
    float4 w4[4];
    float  m = -INFINITY;
#pragma unroll
    for (int r = 0; r < 4; ++r) {
        int i = t + 256 * r;
        l[r]    = logits[a * CB + i];
        w4[r]   = cbook[a * CB + i];
        s_cb[i] = w4[r];
        m = fmaxf(m, l[r]);
    }
#pragma unroll
    for (int off = 32; off >= 1; off >>= 1) m = fmaxf(m, __shfl_down(m, off, 64));
    if ((t & 63) == 0) sredA[t >> 6] = m;
    __syncthreads();
    const float gmax = fmaxf(fmaxf(sredA[0], sredA[1]), fmaxf(sredA[2], sredA[3]));

    float s = 0.f;
#pragma unroll
    for (int r = 0; r < 4; ++r) s += __expf(l[r] - gmax);
#pragma unroll
    for (int off = 32; off >= 1; off >>= 1) s += __shfl_down(s, off, 64);
    if ((t & 63) == 0) sredB[t >> 6] = s;
    __syncthreads();
    const float lse       = gmax + __logf(sredB[0] + sredB[1] + sredB[2] + sredB[3]);
    const float inv_lmbda = 1.0f / lmbda_p[0];
    const float INV_LN2   = 1.4426950408889634f;
#pragma unroll
    for (int r = 0; r < 4; ++r) {
        int i = t + 256 * r;
        float v  = (lse - l[r]) * INV_LN2;     // -log2 pmf  (>= 0)
        s_l2u[i] = v;
        float cc = w4[r].x * w4[r].x + w4[r].y * w4[r].y
                 + w4[r].z * w4[r].z + w4[r].w * w4[r].w;
        s_cnb[i] = cc + v * inv_lmbda;          // ||c||^2 + rate_bias
    }
    __syncthreads();

    // ---- load 4 rows (x pre-scaled by -2 so dist = fma chain into base) ----
    const int nbase = chunk * 1024 + t;
    float4 xm2[4];
#pragma unroll
    for (int r = 0; r < 4; ++r) {
        float4 xv = x[(nbase + 256 * r) * NCB + a];
        xm2[r] = make_float4(-2.f * xv.x, -2.f * xv.y, -2.f * xv.z, -2.f * xv.w);
    }

    float dmin[4] = {INFINITY, INFINITY, INFINITY, INFINITY};
    int   imin[4] = {0, 0, 0, 0};
#pragma unroll 4
    for (int c = 0; c < CB; ++c) {
        const float4 w    = s_cb[c];    // broadcast read, conflict-free
        const float  base = s_cnb[c];
#pragma unroll
        for (int r = 0; r < 4; ++r) {
            float d = fmaf(xm2[r].x, w.x, base);
            d = fmaf(xm2[r].y, w.y, d);
            d = fmaf(xm2[r].z, w.z, d);
            d = fmaf(xm2[r].w, w.w, d);
            bool lt = d < dmin[r];      // strict '<' keeps first index on ties (matches argmin)
            dmin[r] = lt ? d : dmin[r];
            imin[r] = lt ? c : imin[r];
        }
    }

    // ---- outputs: gather winning codeword, accumulate rate ----
    float rsum = 0.f;
#pragma unroll
    for (int r = 0; r < 4; ++r) {
        xhat[(nbase + 256 * r) * NCB + a] = s_cb[imin[r]];
        rsum += s_l2u[imin[r]];
    }
#pragma unroll
    for (int off = 32; off >= 1; off >>= 1) rsum += __shfl_down(rsum, off, 64);
    __shared__ float wsum[4];
    if ((t & 63) == 0) wsum[t >> 6] = rsum;
    __syncthreads();
    if (t == 0) atomicAdd(&tail[0], wsum[0] + wsum[1] + wsum[2] + wsum[3]);
}

extern "C" void kernel_launch(void* const* d_in, const int* in_sizes, int n_in,
                              void* d_out, int out_size, void* d_ws, size_t ws_size,
                              hipStream_t stream) {
    (void)in_sizes; (void)n_in; (void)out_size; (void)d_ws; (void)ws_size;
    const float4* x      = (const float4*)d_in[0];
    const float4* cbook  = (const float4*)d_in[1];
    const float*  logits = (const float*)d_in[2];
    const float*  lmbda  = (const float*)d_in[3];

    float* out  = (float*)d_out;
    float* tail = out + (size_t)N_ROWS * NCB * 4;   // offset 1048576

    zero_tail_kernel<<<1, 64, 0, stream>>>(tail);

    dim3 grid(NCB, N_ROWS / 1024);                  // (16, 16) = 256 blocks
    ecvq_kernel<<<grid, 256, 0, stream>>>(x, cbook, logits, lmbda,
                                          (float4*)d_out, tail);
}